// Round 2
// baseline (2652.688 us; speedup 1.0000x reference)
//
#include <hip/hip_runtime.h>
#include <hip/hip_bf16.h>

#define SEQ   2048
#define NE    768
#define DI    1536
#define DS    16
#define DC    4
#define DTR   48
#define NL    2
#define VOCAB 32000
#define EPS   1e-5f

typedef __hip_bfloat16 bf16;
typedef __bf16 bf16x8 __attribute__((ext_vector_type(8)));
typedef float  f32x4  __attribute__((ext_vector_type(4)));

// ---------------------------------------------------------------------------
// fp32 -> bf16 conversion (for MFMA weight operands). n % 4 == 0.
// ---------------------------------------------------------------------------
__global__ __launch_bounds__(256) void f2b_k(const float* __restrict__ x,
    bf16* __restrict__ y, int n)
{
    int i = (blockIdx.x * 256 + threadIdx.x) * 4;
    if (i >= n) return;
    float4 v = *reinterpret_cast<const float4*>(x + i);
    y[i + 0] = __float2bfloat16(v.x);
    y[i + 1] = __float2bfloat16(v.y);
    y[i + 2] = __float2bfloat16(v.z);
    y[i + 3] = __float2bfloat16(v.w);
}

// ---------------------------------------------------------------------------
// Embedding gather: h[l,:] = E[tokens[l],:]  (fp32 in/out)
// ---------------------------------------------------------------------------
__global__ __launch_bounds__(256) void embed_k(const int* __restrict__ tok,
    const float* __restrict__ E, float* __restrict__ h)
{
    int l = blockIdx.x;
    int t = tok[l];
    for (int k = threadIdx.x; k < NE; k += 256)
        h[(size_t)l * NE + k] = E[(size_t)t * NE + k];
}

// ---------------------------------------------------------------------------
// RMSNorm over last dim (768), bf16 out for MFMA consumption
// ---------------------------------------------------------------------------
__global__ __launch_bounds__(256) void rmsnorm_k(const float* __restrict__ x,
    const float* __restrict__ w, const float* __restrict__ b, bf16* __restrict__ out)
{
    int l = blockIdx.x;
    const float* xr = x + (size_t)l * NE;
    float ss = 0.f;
    for (int k = threadIdx.x; k < NE; k += 256) { float v = xr[k]; ss += v * v; }
    for (int o = 32; o; o >>= 1) ss += __shfl_down(ss, o);
    __shared__ float s4[4];
    if ((threadIdx.x & 63) == 0) s4[threadIdx.x >> 6] = ss;
    __syncthreads();
    float inv = rsqrtf((s4[0] + s4[1] + s4[2] + s4[3]) / NE + EPS);
    for (int k = threadIdx.x; k < NE; k += 256)
        out[(size_t)l * NE + k] = __float2bfloat16(xr[k] * inv * w[k] + b[k]);
}

// ---------------------------------------------------------------------------
// MFMA GEMM: C[M,N] = A[M,K] @ B[N,K]^T, bf16 inputs, fp32 accum, fp32 out.
// Block 256 thr = 4 waves in 2x2; block tile 128x128; wave tile 64x64
// (4x4 of 16x16x32 MFMA). Requires M%128==0, N%128==0, K%32==0.
// Verified layouts (learn_hip m89): A frag m=lane&15,k=quad*8+j; B^T-input
// symmetric; C/D col=lane&15,row=quad*4+r.
// ---------------------------------------------------------------------------
__global__ __launch_bounds__(256) void gemm_bt(const bf16* __restrict__ Abf,
    const bf16* __restrict__ Bbf, float* __restrict__ Cout, int M, int N, int K)
{
    const int wave = threadIdx.x >> 6;
    const int lane = threadIdx.x & 63;
    const int wm = wave >> 1, wn = wave & 1;
    const int tm = blockIdx.y * 128 + wm * 64;
    const int tn = blockIdx.x * 128 + wn * 64;
    const int r16 = lane & 15, quad = lane >> 4;

    const __bf16* A = reinterpret_cast<const __bf16*>(Abf);
    const __bf16* B = reinterpret_cast<const __bf16*>(Bbf);

    f32x4 zero = {0.f, 0.f, 0.f, 0.f};
    f32x4 acc[4][4];
#pragma unroll
    for (int i = 0; i < 4; i++)
#pragma unroll
        for (int j = 0; j < 4; j++) acc[i][j] = zero;

    const __bf16* Ab = A + (size_t)(tm + r16) * K + quad * 8;
    const __bf16* Bb = B + (size_t)(tn + r16) * K + quad * 8;

    for (int k = 0; k < K; k += 32) {
        bf16x8 av[4], bv[4];
#pragma unroll
        for (int i = 0; i < 4; i++)
            av[i] = *reinterpret_cast<const bf16x8*>(Ab + (size_t)i * 16 * K + k);
#pragma unroll
        for (int j = 0; j < 4; j++)
            bv[j] = *reinterpret_cast<const bf16x8*>(Bb + (size_t)j * 16 * K + k);
#pragma unroll
        for (int i = 0; i < 4; i++)
#pragma unroll
            for (int j = 0; j < 4; j++)
                acc[i][j] = __builtin_amdgcn_mfma_f32_16x16x32_bf16(av[i], bv[j], acc[i][j], 0, 0, 0);
    }

#pragma unroll
    for (int i = 0; i < 4; i++) {
        int cm0 = tm + i * 16 + quad * 4;
#pragma unroll
        for (int j = 0; j < 4; j++) {
            int cn = tn + j * 16 + r16;
#pragma unroll
            for (int r = 0; r < 4; r++)
                Cout[(size_t)(cm0 + r) * N + cn] = acc[i][j][r];
        }
    }
}

// ---------------------------------------------------------------------------
// Depthwise causal conv (k=4) + bias + SiLU. xr is [SEQ, 2*DI], x = cols 0..DI-1.
// out u fp32 [SEQ, DI]
// ---------------------------------------------------------------------------
__global__ __launch_bounds__(256) void conv_silu_k(const float* __restrict__ xr,
    const float* __restrict__ cw, const float* __restrict__ cb, float* __restrict__ u)
{
    int idx = blockIdx.x * 256 + threadIdx.x;   // over SEQ*DI
    int l = idx / DI, d = idx - l * DI;
    float s = cb[d];
#pragma unroll
    for (int t = 0; t < DC; t++) {
        int ls = l - (DC - 1) + t;
        if (ls >= 0) s += xr[(size_t)ls * (2 * DI) + d] * cw[d * DC + t];
    }
    u[idx] = s / (1.f + expf(-s));
}

// ---------------------------------------------------------------------------
// x_proj: xdbl[l, j] = sum_k u[l,k] * xpw[j,k], j < 80. One wave per (l,j).
// ---------------------------------------------------------------------------
__global__ __launch_bounds__(256) void xproj_k(const float* __restrict__ u,
    const float* __restrict__ xpw, float* __restrict__ xdbl)
{
    int gw = blockIdx.x * 4 + (threadIdx.x >> 6);
    int l = gw / 80, j = gw - l * 80;
    int lane = threadIdx.x & 63;
    const float* ur = u + (size_t)l * DI;
    const float* wr = xpw + (size_t)j * DI;
    float s = 0.f;
    for (int k = lane; k < DI; k += 64) s += ur[k] * wr[k];
    for (int o = 32; o; o >>= 1) s += __shfl_down(s, o);
    if (lane == 0) xdbl[(size_t)l * 80 + j] = s;
}

// ---------------------------------------------------------------------------
// dt_proj + softplus: delta[l,d] = softplus(xdbl[l,:48] . dtw[d,:] + dtb[d])
// ---------------------------------------------------------------------------
__global__ __launch_bounds__(256) void dtproj_k(const float* __restrict__ xdbl,
    const float* __restrict__ dtw, const float* __restrict__ dtb, float* __restrict__ delta)
{
    int l = blockIdx.y;
    int d = blockIdx.x * 256 + threadIdx.x;
    __shared__ float xs[DTR];
    if (threadIdx.x < DTR) xs[threadIdx.x] = xdbl[(size_t)l * 80 + threadIdx.x];
    __syncthreads();
    float s = dtb[d];
    const float* wr = dtw + (size_t)d * DTR;
#pragma unroll
    for (int k = 0; k < DTR; k++) s += xs[k] * wr[k];
    // stable softplus = max(s,0) + log1p(exp(-|s|))
    delta[(size_t)l * DI + d] = fmaxf(s, 0.f) + log1pf(expf(-fabsf(s)));
}

// ---------------------------------------------------------------------------
// Selective scan. Thread = (d, n): 16 d-groups x 16 states per block.
// B = xdbl[:, 48:64], C = xdbl[:, 64:80]. y[l,d] = sum_n state*C (shfl reduce).
// Sequential over L with next-step prefetch.
// ---------------------------------------------------------------------------
__global__ __launch_bounds__(256) void scan_k(const float* __restrict__ delta,
    const float* __restrict__ u, const float* __restrict__ xdbl,
    const float* __restrict__ alog, float* __restrict__ y)
{
    int dg = threadIdx.x >> 4;       // 0..15
    int n  = threadIdx.x & 15;
    int d  = blockIdx.x * 16 + dg;
    float A = -expf(alog[(size_t)d * DS + n]);
    float st = 0.f;
    float dl = delta[d], ul = u[d];
    float Bn = xdbl[DTR + n], Cn = xdbl[DTR + DS + n];
    for (int l = 0; l < SEQ; l++) {
        float dl2 = 0.f, ul2 = 0.f, Bn2 = 0.f, Cn2 = 0.f;
        if (l + 1 < SEQ) {
            size_t o  = (size_t)(l + 1) * DI + d;
            size_t o2 = (size_t)(l + 1) * 80;
            dl2 = delta[o]; ul2 = u[o];
            Bn2 = xdbl[o2 + DTR + n]; Cn2 = xdbl[o2 + DTR + DS + n];
        }
        st = expf(dl * A) * st + dl * ul * Bn;
        float p = st * Cn;
        p += __shfl_down(p, 8);
        p += __shfl_down(p, 4);
        p += __shfl_down(p, 2);
        p += __shfl_down(p, 1);
        if (n == 0) y[(size_t)l * DI + d] = p;
        dl = dl2; ul = ul2; Bn = Bn2; Cn = Cn2;
    }
}

// ---------------------------------------------------------------------------
// y = (y_scan + u*D) * silu(res);  res = xr[:, DI:2*DI]. bf16 out for GEMM.
// ---------------------------------------------------------------------------
__global__ __launch_bounds__(256) void yfuse_k(const float* __restrict__ ysc,
    const float* __restrict__ u, const float* __restrict__ Dp,
    const float* __restrict__ xr, bf16* __restrict__ ybf)
{
    int idx = blockIdx.x * 256 + threadIdx.x;
    int l = idx / DI, d = idx - l * DI;
    float yv = ysc[idx] + u[idx] * Dp[d];
    float r = xr[(size_t)l * (2 * DI) + DI + d];
    yv *= r / (1.f + expf(-r));
    ybf[idx] = __float2bfloat16(yv);
}

// ---------------------------------------------------------------------------
// h += tmp
// ---------------------------------------------------------------------------
__global__ __launch_bounds__(256) void add_k(float* __restrict__ h, const float* __restrict__ t)
{
    int i = blockIdx.x * 256 + threadIdx.x;
    h[i] += t[i];
}

// ---------------------------------------------------------------------------
extern "C" void kernel_launch(void* const* d_in, const int* in_sizes, int n_in,
                              void* d_out, int out_size, void* d_ws, size_t ws_size,
                              hipStream_t stream)
{
    const int*   tokens  = (const int*)  d_in[0];
    const float* E       = (const float*)d_in[1];
    const float* in_w    = (const float*)d_in[2];
    const float* conv_w  = (const float*)d_in[3];
    const float* conv_b  = (const float*)d_in[4];
    const float* xp_w    = (const float*)d_in[5];
    const float* dt_w    = (const float*)d_in[6];
    const float* dt_b    = (const float*)d_in[7];
    const float* A_log   = (const float*)d_in[8];
    const float* D_p     = (const float*)d_in[9];
    const float* out_w   = (const float*)d_in[10];
    const float* norm_w  = (const float*)d_in[11];
    const float* norm_b  = (const float*)d_in[12];
    const float* normf_w = (const float*)d_in[13];
    const float* normf_b = (const float*)d_in[14];

    char* ws = (char*)d_ws;
    size_t off = 0;
    auto alloc = [&](size_t bytes) -> void* {
        void* p = ws + off;
        off = (off + bytes + 255) & ~(size_t)255;
        return p;
    };

    float* h     = (float*)alloc((size_t)SEQ * NE * 4);
    bf16*  xn    = (bf16*) alloc((size_t)SEQ * NE * 2);
    float* xr    = (float*)alloc((size_t)SEQ * 2 * DI * 4);
    float* u     = (float*)alloc((size_t)SEQ * DI * 4);
    float* xdbl  = (float*)alloc((size_t)SEQ * 80 * 4);
    float* delta = (float*)alloc((size_t)SEQ * DI * 4);
    float* ysc   = (float*)alloc((size_t)SEQ * DI * 4);
    bf16*  ybf   = (bf16*) alloc((size_t)SEQ * DI * 2);
    float* tmp   = (float*)alloc((size_t)SEQ * NE * 4);
    bf16*  hf    = (bf16*) alloc((size_t)SEQ * NE * 2);
    bf16*  Ebf   = (bf16*) alloc((size_t)VOCAB * NE * 2);           // 49 MB
    bf16*  wbuf  = (bf16*) alloc((size_t)2 * DI * NE * 2);          // reused in/out proj weights

    // Convert E once per launch (re-poisoned ws each call, so always).
    {
        int n = VOCAB * NE;
        f2b_k<<<(n / 4 + 255) / 256, 256, 0, stream>>>(E, Ebf, n);
    }

    embed_k<<<SEQ, 256, 0, stream>>>(tokens, E, h);

    for (int L = 0; L < NL; L++) {
        rmsnorm_k<<<SEQ, 256, 0, stream>>>(h, norm_w + (size_t)L * NE, norm_b + (size_t)L * NE, xn);

        {
            int n = 2 * DI * NE;
            f2b_k<<<(n / 4 + 255) / 256, 256, 0, stream>>>(in_w + (size_t)L * n, wbuf, n);
        }
        gemm_bt<<<dim3(2 * DI / 128, SEQ / 128), 256, 0, stream>>>(
            xn, wbuf, xr, SEQ, 2 * DI, NE);

        conv_silu_k<<<SEQ * DI / 256, 256, 0, stream>>>(
            xr, conv_w + (size_t)L * DI * DC, conv_b + (size_t)L * DI, u);

        xproj_k<<<SEQ * 80 / 4, 256, 0, stream>>>(u, xp_w + (size_t)L * 80 * DI, xdbl);

        dtproj_k<<<dim3(DI / 256, SEQ), 256, 0, stream>>>(
            xdbl, dt_w + (size_t)L * DI * DTR, dt_b + (size_t)L * DI, delta);

        scan_k<<<DI / 16, 256, 0, stream>>>(delta, u, xdbl, A_log + (size_t)L * DI * DS, ysc);

        yfuse_k<<<SEQ * DI / 256, 256, 0, stream>>>(ysc, u, D_p + (size_t)L * DI, xr, ybf);

        {
            int n = NE * DI;
            f2b_k<<<(n / 4 + 255) / 256, 256, 0, stream>>>(out_w + (size_t)L * n, wbuf, n);
        }
        gemm_bt<<<dim3(NE / 128, SEQ / 128), 256, 0, stream>>>(
            ybf, wbuf, tmp, SEQ, NE, DI);

        add_k<<<SEQ * NE / 256, 256, 0, stream>>>(h, tmp);
    }

    rmsnorm_k<<<SEQ, 256, 0, stream>>>(h, normf_w, normf_b, hf);

    gemm_bt<<<dim3(VOCAB / 128, SEQ / 128), 256, 0, stream>>>(
        hf, Ebf, (float*)d_out, SEQ, VOCAB, NE);
}

// Round 3
// 1634.924 us; speedup vs baseline: 1.6225x; 1.6225x over previous
//
#include <hip/hip_runtime.h>
#include <hip/hip_bf16.h>

#define SEQ   2048
#define NE    768
#define DI    1536
#define DS    16
#define DC    4
#define DTR   48
#define NL    2
#define VOCAB 32000
#define EPS   1e-5f
#define CHUNK 128
#define NCH   (SEQ / CHUNK)

typedef __hip_bfloat16 bf16;
typedef __bf16 bf16x8 __attribute__((ext_vector_type(8)));
typedef float  f32x4  __attribute__((ext_vector_type(4)));

// ---------------------------------------------------------------------------
// fp32 -> bf16 conversion (for MFMA weight operands). n % 4 == 0.
// ---------------------------------------------------------------------------
__global__ __launch_bounds__(256) void f2b_k(const float* __restrict__ x,
    bf16* __restrict__ y, int n)
{
    int i = (blockIdx.x * 256 + threadIdx.x) * 4;
    if (i >= n) return;
    float4 v = *reinterpret_cast<const float4*>(x + i);
    y[i + 0] = __float2bfloat16(v.x);
    y[i + 1] = __float2bfloat16(v.y);
    y[i + 2] = __float2bfloat16(v.z);
    y[i + 3] = __float2bfloat16(v.w);
}

// ---------------------------------------------------------------------------
// Embedding gather: h[l,:] = E[tokens[l],:]  (fp32 in/out)
// ---------------------------------------------------------------------------
__global__ __launch_bounds__(256) void embed_k(const int* __restrict__ tok,
    const float* __restrict__ E, float* __restrict__ h)
{
    int l = blockIdx.x;
    int t = tok[l];
    for (int k = threadIdx.x; k < NE; k += 256)
        h[(size_t)l * NE + k] = E[(size_t)t * NE + k];
}

// ---------------------------------------------------------------------------
// RMSNorm over last dim (768), bf16 out for MFMA consumption
// ---------------------------------------------------------------------------
__global__ __launch_bounds__(256) void rmsnorm_k(const float* __restrict__ x,
    const float* __restrict__ w, const float* __restrict__ b, bf16* __restrict__ out)
{
    int l = blockIdx.x;
    const float* xr = x + (size_t)l * NE;
    float ss = 0.f;
    for (int k = threadIdx.x; k < NE; k += 256) { float v = xr[k]; ss += v * v; }
    for (int o = 32; o; o >>= 1) ss += __shfl_down(ss, o);
    __shared__ float s4[4];
    if ((threadIdx.x & 63) == 0) s4[threadIdx.x >> 6] = ss;
    __syncthreads();
    float inv = rsqrtf((s4[0] + s4[1] + s4[2] + s4[3]) / NE + EPS);
    for (int k = threadIdx.x; k < NE; k += 256)
        out[(size_t)l * NE + k] = __float2bfloat16(xr[k] * inv * w[k] + b[k]);
}

// ---------------------------------------------------------------------------
// MFMA GEMM: C[M,N] = A[M,K] @ B[N,K]^T, bf16 inputs, fp32 accum, fp32 out.
// Block 256 thr = 4 waves in 2x2; block tile 128x128; wave tile 64x64
// (4x4 of 16x16x32 MFMA). Requires M%128==0, N%128==0, K%32==0.
// ---------------------------------------------------------------------------
__global__ __launch_bounds__(256) void gemm_bt(const bf16* __restrict__ Abf,
    const bf16* __restrict__ Bbf, float* __restrict__ Cout, int M, int N, int K)
{
    const int wave = threadIdx.x >> 6;
    const int lane = threadIdx.x & 63;
    const int wm = wave >> 1, wn = wave & 1;
    const int tm = blockIdx.y * 128 + wm * 64;
    const int tn = blockIdx.x * 128 + wn * 64;
    const int r16 = lane & 15, quad = lane >> 4;

    const __bf16* A = reinterpret_cast<const __bf16*>(Abf);
    const __bf16* B = reinterpret_cast<const __bf16*>(Bbf);

    f32x4 zero = {0.f, 0.f, 0.f, 0.f};
    f32x4 acc[4][4];
#pragma unroll
    for (int i = 0; i < 4; i++)
#pragma unroll
        for (int j = 0; j < 4; j++) acc[i][j] = zero;

    const __bf16* Ab = A + (size_t)(tm + r16) * K + quad * 8;
    const __bf16* Bb = B + (size_t)(tn + r16) * K + quad * 8;

    for (int k = 0; k < K; k += 32) {
        bf16x8 av[4], bv[4];
#pragma unroll
        for (int i = 0; i < 4; i++)
            av[i] = *reinterpret_cast<const bf16x8*>(Ab + (size_t)i * 16 * K + k);
#pragma unroll
        for (int j = 0; j < 4; j++)
            bv[j] = *reinterpret_cast<const bf16x8*>(Bb + (size_t)j * 16 * K + k);
#pragma unroll
        for (int i = 0; i < 4; i++)
#pragma unroll
            for (int j = 0; j < 4; j++)
                acc[i][j] = __builtin_amdgcn_mfma_f32_16x16x32_bf16(av[i], bv[j], acc[i][j], 0, 0, 0);
    }

#pragma unroll
    for (int i = 0; i < 4; i++) {
        int cm0 = tm + i * 16 + quad * 4;
#pragma unroll
        for (int j = 0; j < 4; j++) {
            int cn = tn + j * 16 + r16;
#pragma unroll
            for (int r = 0; r < 4; r++)
                Cout[(size_t)(cm0 + r) * N + cn] = acc[i][j][r];
        }
    }
}

// ---------------------------------------------------------------------------
// Depthwise causal conv (k=4) + bias + SiLU.
// ---------------------------------------------------------------------------
__global__ __launch_bounds__(256) void conv_silu_k(const float* __restrict__ xr,
    const float* __restrict__ cw, const float* __restrict__ cb, float* __restrict__ u)
{
    int idx = blockIdx.x * 256 + threadIdx.x;   // over SEQ*DI
    int l = idx / DI, d = idx - l * DI;
    float s = cb[d];
#pragma unroll
    for (int t = 0; t < DC; t++) {
        int ls = l - (DC - 1) + t;
        if (ls >= 0) s += xr[(size_t)ls * (2 * DI) + d] * cw[d * DC + t];
    }
    u[idx] = s / (1.f + expf(-s));
}

// ---------------------------------------------------------------------------
// x_proj: xdbl[l, j] = sum_k u[l,k] * xpw[j,k], j < 80. One wave per (l,j).
// ---------------------------------------------------------------------------
__global__ __launch_bounds__(256) void xproj_k(const float* __restrict__ u,
    const float* __restrict__ xpw, float* __restrict__ xdbl)
{
    int gw = blockIdx.x * 4 + (threadIdx.x >> 6);
    int l = gw / 80, j = gw - l * 80;
    int lane = threadIdx.x & 63;
    const float* ur = u + (size_t)l * DI;
    const float* wr = xpw + (size_t)j * DI;
    float s = 0.f;
    for (int k = lane; k < DI; k += 64) s += ur[k] * wr[k];
    for (int o = 32; o; o >>= 1) s += __shfl_down(s, o);
    if (lane == 0) xdbl[(size_t)l * 80 + j] = s;
}

// ---------------------------------------------------------------------------
// dt_proj + softplus
// ---------------------------------------------------------------------------
__global__ __launch_bounds__(256) void dtproj_k(const float* __restrict__ xdbl,
    const float* __restrict__ dtw, const float* __restrict__ dtb, float* __restrict__ delta)
{
    int l = blockIdx.y;
    int d = blockIdx.x * 256 + threadIdx.x;
    __shared__ float xs[DTR];
    if (threadIdx.x < DTR) xs[threadIdx.x] = xdbl[(size_t)l * 80 + threadIdx.x];
    __syncthreads();
    float s = dtb[d];
    const float* wr = dtw + (size_t)d * DTR;
#pragma unroll
    for (int k = 0; k < DTR; k++) s += xs[k] * wr[k];
    delta[(size_t)l * DI + d] = fmaxf(s, 0.f) + log1pf(expf(-fabsf(s)));
}

// ---------------------------------------------------------------------------
// Chunked selective scan, pass 1: per chunk c, per (d,n): local end-state S
// (from zero init) and decay product P = prod(exp(delta*A)) over the chunk.
// Grid (DI/16, NCH), block 256 = 16 d-groups x 16 n.
// ---------------------------------------------------------------------------
__global__ __launch_bounds__(256) void scan1_k(const float* __restrict__ delta,
    const float* __restrict__ u, const float* __restrict__ xdbl,
    const float* __restrict__ alog, float* __restrict__ S, float* __restrict__ P)
{
    int dg = threadIdx.x >> 4, n = threadIdx.x & 15;
    int d = blockIdx.x * 16 + dg;
    int c = blockIdx.y;
    float A = -expf(alog[(size_t)d * DS + n]);
    float st = 0.f, pr = 1.f;
    int l0 = c * CHUNK;
#pragma unroll 4
    for (int t = 0; t < CHUNK; t++) {
        int l = l0 + t;
        float dl = delta[(size_t)l * DI + d];
        float ul = u[(size_t)l * DI + d];
        float Bn = xdbl[(size_t)l * 80 + DTR + n];
        float a = expf(dl * A);
        st = a * st + dl * ul * Bn;
        pr *= a;
    }
    size_t o = ((size_t)c * DI + d) * DS + n;
    S[o] = st;
    P[o] = pr;
}

// ---------------------------------------------------------------------------
// Pass 2: sequential combine over the 16 chunks -> incoming state per chunk.
// 96 blocks x 256 threads, thread = flat (d,n).
// ---------------------------------------------------------------------------
__global__ __launch_bounds__(256) void scan2_k(const float* __restrict__ S,
    const float* __restrict__ P, float* __restrict__ sin_)
{
    int i = blockIdx.x * 256 + threadIdx.x;   // over DI*DS
    float run = 0.f;
#pragma unroll
    for (int c = 0; c < NCH; c++) {
        size_t o = (size_t)c * DI * DS + i;
        sin_[o] = run;
        run = S[o] + P[o] * run;
    }
}

// ---------------------------------------------------------------------------
// Pass 3: re-run each chunk from its incoming state, compute y, fuse
// (y + u*D) * silu(res) gate, write bf16 for the out_proj GEMM.
// ---------------------------------------------------------------------------
__global__ __launch_bounds__(256) void scan3_k(const float* __restrict__ delta,
    const float* __restrict__ u, const float* __restrict__ xdbl,
    const float* __restrict__ alog, const float* __restrict__ sin_,
    const float* __restrict__ Dp, const float* __restrict__ xr,
    bf16* __restrict__ ybf)
{
    int dg = threadIdx.x >> 4, n = threadIdx.x & 15;
    int d = blockIdx.x * 16 + dg;
    int c = blockIdx.y;
    float A = -expf(alog[(size_t)d * DS + n]);
    float Dv = Dp[d];
    float st = sin_[((size_t)c * DI + d) * DS + n];
    int l0 = c * CHUNK;
#pragma unroll 2
    for (int t = 0; t < CHUNK; t++) {
        int l = l0 + t;
        float dl = delta[(size_t)l * DI + d];
        float ul = u[(size_t)l * DI + d];
        float Bn = xdbl[(size_t)l * 80 + DTR + n];
        float Cn = xdbl[(size_t)l * 80 + DTR + DS + n];
        float a = expf(dl * A);
        st = a * st + dl * ul * Bn;
        float p = st * Cn;
        p += __shfl_down(p, 8);
        p += __shfl_down(p, 4);
        p += __shfl_down(p, 2);
        p += __shfl_down(p, 1);
        if (n == 0) {
            float r = xr[(size_t)l * (2 * DI) + DI + d];
            float yv = (p + ul * Dv) * (r / (1.f + expf(-r)));
            ybf[(size_t)l * DI + d] = __float2bfloat16(yv);
        }
    }
}

// ---------------------------------------------------------------------------
// h += tmp
// ---------------------------------------------------------------------------
__global__ __launch_bounds__(256) void add_k(float* __restrict__ h, const float* __restrict__ t)
{
    int i = blockIdx.x * 256 + threadIdx.x;
    h[i] += t[i];
}

// ---------------------------------------------------------------------------
extern "C" void kernel_launch(void* const* d_in, const int* in_sizes, int n_in,
                              void* d_out, int out_size, void* d_ws, size_t ws_size,
                              hipStream_t stream)
{
    const int*   tokens  = (const int*)  d_in[0];
    const float* E       = (const float*)d_in[1];
    const float* in_w    = (const float*)d_in[2];
    const float* conv_w  = (const float*)d_in[3];
    const float* conv_b  = (const float*)d_in[4];
    const float* xp_w    = (const float*)d_in[5];
    const float* dt_w    = (const float*)d_in[6];
    const float* dt_b    = (const float*)d_in[7];
    const float* A_log   = (const float*)d_in[8];
    const float* D_p     = (const float*)d_in[9];
    const float* out_w   = (const float*)d_in[10];
    const float* norm_w  = (const float*)d_in[11];
    const float* norm_b  = (const float*)d_in[12];
    const float* normf_w = (const float*)d_in[13];
    const float* normf_b = (const float*)d_in[14];

    char* ws = (char*)d_ws;
    size_t off = 0;
    auto alloc = [&](size_t bytes) -> void* {
        void* p = ws + off;
        off = (off + bytes + 255) & ~(size_t)255;
        return p;
    };

    float* h     = (float*)alloc((size_t)SEQ * NE * 4);
    bf16*  xn    = (bf16*) alloc((size_t)SEQ * NE * 2);
    float* xr    = (float*)alloc((size_t)SEQ * 2 * DI * 4);
    float* u     = (float*)alloc((size_t)SEQ * DI * 4);
    float* xdbl  = (float*)alloc((size_t)SEQ * 80 * 4);
    float* delta = (float*)alloc((size_t)SEQ * DI * 4);
    bf16*  ybf   = (bf16*) alloc((size_t)SEQ * DI * 2);
    float* tmp   = (float*)alloc((size_t)SEQ * NE * 4);
    bf16*  hf    = (bf16*) alloc((size_t)SEQ * NE * 2);
    bf16*  Ebf   = (bf16*) alloc((size_t)VOCAB * NE * 2);           // 49 MB
    bf16*  wbuf  = (bf16*) alloc((size_t)2 * DI * NE * 2);          // reused proj weights
    float* Sbuf  = (float*)alloc((size_t)NCH * DI * DS * 4);
    float* Pbuf  = (float*)alloc((size_t)NCH * DI * DS * 4);
    float* Sin   = (float*)alloc((size_t)NCH * DI * DS * 4);

    {
        int n = VOCAB * NE;
        f2b_k<<<(n / 4 + 255) / 256, 256, 0, stream>>>(E, Ebf, n);
    }

    embed_k<<<SEQ, 256, 0, stream>>>(tokens, E, h);

    for (int L = 0; L < NL; L++) {
        rmsnorm_k<<<SEQ, 256, 0, stream>>>(h, norm_w + (size_t)L * NE, norm_b + (size_t)L * NE, xn);

        {
            int n = 2 * DI * NE;
            f2b_k<<<(n / 4 + 255) / 256, 256, 0, stream>>>(in_w + (size_t)L * n, wbuf, n);
        }
        gemm_bt<<<dim3(2 * DI / 128, SEQ / 128), 256, 0, stream>>>(
            xn, wbuf, xr, SEQ, 2 * DI, NE);

        conv_silu_k<<<SEQ * DI / 256, 256, 0, stream>>>(
            xr, conv_w + (size_t)L * DI * DC, conv_b + (size_t)L * DI, u);

        xproj_k<<<SEQ * 80 / 4, 256, 0, stream>>>(u, xp_w + (size_t)L * 80 * DI, xdbl);

        dtproj_k<<<dim3(DI / 256, SEQ), 256, 0, stream>>>(
            xdbl, dt_w + (size_t)L * DI * DTR, dt_b + (size_t)L * DI, delta);

        const float* alog = A_log + (size_t)L * DI * DS;
        scan1_k<<<dim3(DI / 16, NCH), 256, 0, stream>>>(delta, u, xdbl, alog, Sbuf, Pbuf);
        scan2_k<<<DI * DS / 256, 256, 0, stream>>>(Sbuf, Pbuf, Sin);
        scan3_k<<<dim3(DI / 16, NCH), 256, 0, stream>>>(
            delta, u, xdbl, alog, Sin, D_p + (size_t)L * DI, xr, ybf);

        {
            int n = NE * DI;
            f2b_k<<<(n / 4 + 255) / 256, 256, 0, stream>>>(out_w + (size_t)L * n, wbuf, n);
        }
        gemm_bt<<<dim3(NE / 128, SEQ / 128), 256, 0, stream>>>(
            ybf, wbuf, tmp, SEQ, NE, DI);

        add_k<<<SEQ * NE / 256, 256, 0, stream>>>(h, tmp);
    }

    rmsnorm_k<<<SEQ, 256, 0, stream>>>(h, normf_w, normf_b, hf);

    gemm_bt<<<dim3(VOCAB / 128, SEQ / 128), 256, 0, stream>>>(
        hf, Ebf, (float*)d_out, SEQ, VOCAB, NE);
}